// Round 20
// baseline (192.102 us; speedup 1.0000x reference)
//
#include <hip/hip_runtime.h>
#include <cmath>

#define Nn    8192
#define INF_  512
#define OUTF  64

typedef __attribute__((ext_vector_type(4))) int   i4;
typedef __attribute__((ext_vector_type(4))) float f4v;
typedef __attribute__((ext_vector_type(8))) short s8;
typedef __attribute__((ext_vector_type(4))) float f32x4;
typedef unsigned long long u64;

__device__ __forceinline__ float lrelu(float v) { return fmaxf(v, 0.2f * v); }

__device__ __forceinline__ unsigned int f2bf(float f) {
    unsigned int u = __float_as_uint(f);
    u = (u + 0x7FFFu + ((u >> 16) & 1u)) >> 16;
    return u;
}

// ---------------------------------------------------------------------------
// k1: Wh = x @ W -> WhT bf16 [64][N]; Wh1 = Wh@a[:64]; Wh2 = Wh@a[64:].
// DENSE x read (R15 exact). 1024 thr; grid N/16 = 512.
// ---------------------------------------------------------------------------
__global__ __launch_bounds__(1024, 8) void k1_wh(
    const float* __restrict__ x, const float* __restrict__ W,
    const float* __restrict__ a, unsigned short* __restrict__ WhT,
    float* __restrict__ Wh1, float* __restrict__ Wh2)
{
    __shared__ float xs[16][520];             // 33.3 KB x slab (padded)
    __shared__ float part[3][16][64];         // 12 KB k-slice partials
    __shared__ unsigned short stage[64][16];  // 2 KB bf16 transpose stage
    const int t    = threadIdx.x;
    const int row0 = blockIdx.x * 16;

    #pragma unroll
    for (int s2 = 0; s2 < 2; ++s2) {
        const int idx = s2 * 4096 + 4 * t;
        const f4v v = __builtin_nontemporal_load(
            (const f4v*)(x + (size_t)row0 * INF_ + idx));
        *(f4v*)&xs[idx >> 9][idx & 511] = v;
    }
    __syncthreads();

    const int s    = t >> 8;                  // k-slice 0..3
    const int r    = (t >> 4) & 15;           // row
    const int cg   = (t & 15) << 2;           // col group (4 cols)
    const int row  = row0 + r;
    const float* __restrict__ Wp = W + (size_t)s * 128 * OUTF;

    float4 acc = make_float4(0.f, 0.f, 0.f, 0.f);
    for (int k = 0; k < 128; k += 4) {
        const float4 xv = *(const float4*)&xs[r][s * 128 + k];
        const float* wp = Wp + (size_t)k * OUTF + cg;
        const float4 w0 = *(const float4*)(wp);
        const float4 w1 = *(const float4*)(wp + OUTF);
        const float4 w2 = *(const float4*)(wp + 2 * OUTF);
        const float4 w3 = *(const float4*)(wp + 3 * OUTF);
        acc.x += xv.x * w0.x + xv.y * w1.x + xv.z * w2.x + xv.w * w3.x;
        acc.y += xv.x * w0.y + xv.y * w1.y + xv.z * w2.y + xv.w * w3.y;
        acc.z += xv.x * w0.z + xv.y * w1.z + xv.z * w2.z + xv.w * w3.z;
        acc.w += xv.x * w0.w + xv.y * w1.w + xv.z * w2.w + xv.w * w3.w;
    }
    if (s > 0) *(float4*)&part[s - 1][r][cg] = acc;
    __syncthreads();
    if (s == 0) {
        const float4 pa = *(const float4*)&part[0][r][cg];
        const float4 pb = *(const float4*)&part[1][r][cg];
        const float4 pc = *(const float4*)&part[2][r][cg];
        acc.x += pa.x + pb.x + pc.x;
        acc.y += pa.y + pb.y + pc.y;
        acc.z += pa.z + pb.z + pc.z;
        acc.w += pa.w + pb.w + pc.w;
        stage[cg + 0][r] = (unsigned short)f2bf(acc.x);
        stage[cg + 1][r] = (unsigned short)f2bf(acc.y);
        stage[cg + 2][r] = (unsigned short)f2bf(acc.z);
        stage[cg + 3][r] = (unsigned short)f2bf(acc.w);

        float p1 = acc.x * a[cg]        + acc.y * a[cg + 1]
                 + acc.z * a[cg + 2]    + acc.w * a[cg + 3];
        float p2 = acc.x * a[OUTF + cg]     + acc.y * a[OUTF + cg + 1]
                 + acc.z * a[OUTF + cg + 2] + acc.w * a[OUTF + cg + 3];
        #pragma unroll
        for (int off = 8; off; off >>= 1) {
            p1 += __shfl_xor(p1, off);
            p2 += __shfl_xor(p2, off);
        }
        if ((t & 15) == 0) { Wh1[row] = p1; Wh2[row] = p2; }
    }
    __syncthreads();
    if (t < 256) {
        const int col = t >> 2;
        const int q   = t & 3;
        const u64 v = *(const u64*)&stage[col][q * 4];
        *(u64*)(WhT + (size_t)col * Nn + row0 + q * 4) = v;
    }
}

// ---------------------------------------------------------------------------
// k2: FUSED, 16 rows/block, 1024 thr = 16 waves, grid N/16 = 512.
//  Phase A (DUPLEX dense sweep — the lever): per row r: 2 dense 16 KB read
//    steps (3-deep nt pipeline, exps kept in regs) -> butterfly partial ->
//    sm_Sp flush -> lgkm-only barrier (read pipeline survives; no vmcnt
//    drain) -> every thread folds sm_Sp[r][0..15] -> is_r -> block writes
//    row r's 32 KB of NORMALIZED att densely (reg-cached p * is_r, nt).
//    Read and write HBM streams now alternate every 32 KB for the whole
//    sweep -> duplex overlap within every block.
//  Phase B (pure LDS+MFMA, no global stores): per 256-j chunk: bf16 p tile
//    from bm8 -> XOR-swizzled LDS dbuf; 2 mfma/chunk (ct=w&3, kq=w>>2),
//    1-chunk b-frag prefetch; lgkmcnt(0)+s_barrier per chunk.
//  Epilogue: 4-way kq reduce, ELU, store out.
// ---------------------------------------------------------------------------
__global__ __launch_bounds__(1024, 8) void k2_fused(
    const int* __restrict__ adj, const unsigned short* __restrict__ WhT,
    const float* __restrict__ Wh1, const float* __restrict__ Wh2,
    float* __restrict__ outp, float* __restrict__ att)
{
    __shared__ unsigned char bm8[16][2048];                    // 32 KB masks
    __shared__ alignas(16) unsigned short att_t[2][16 * 256];  // 16 KB
    __shared__ float red[3][4][16][16];                        // 12 KB
    __shared__ float sm_Sp[16][16];                            // 1 KB
    __shared__ float sm_is[16];

    const int t    = threadIdx.x;
    const int lane = t & 63;
    const int w    = t >> 6;               // wave id; phase B row = w
    const int row0 = blockIdx.x * 16;

    const int j0 = 4 * t;                  // this thread's j within half-row
    const f4v w4a = *(const f4v*)(Wh2 + j0);          // half 0 cols
    const f4v w4b = *(const f4v*)(Wh2 + 4096 + j0);   // half 1 cols

    // ---------------- Phase A: duplex dense sweep ---------------------------
    {
        const i4* __restrict__ asrc = (const i4*)(adj + (size_t)row0 * Nn);
        float* __restrict__ attb = att + (size_t)row0 * Nn;
        float Sp = 0.f;
        float pq0 = 0.f, pq1 = 0.f, pq2 = 0.f, pq3 = 0.f;   // half-0 p values
        i4 p0 = __builtin_nontemporal_load(asrc + t);
        i4 p1 = __builtin_nontemporal_load(asrc + 1024 + t);
        i4 p2 = __builtin_nontemporal_load(asrc + 2048 + t);
        #pragma unroll
        for (int s = 0; s < 32; ++s) {
            const int r = s >> 1, h = s & 1;
            const i4 av = p0;
            p0 = p1; p1 = p2;
            if (s < 29)
                p2 = __builtin_nontemporal_load(asrc + (s + 3) * 1024 + t);
            const f4v w4 = h ? w4b : w4a;
            const float h1r = Wh1[row0 + r];
            const int nib = (av.x != 0 ? 1 : 0) | (av.y != 0 ? 2 : 0)
                          | (av.z != 0 ? 4 : 0) | (av.w != 0 ? 8 : 0);
            const float q0 = (nib & 1) ? __expf(lrelu(h1r + w4.x)) : 0.f;
            const float q1 = (nib & 2) ? __expf(lrelu(h1r + w4.y)) : 0.f;
            const float q2 = (nib & 4) ? __expf(lrelu(h1r + w4.z)) : 0.f;
            const float q3 = (nib & 8) ? __expf(lrelu(h1r + w4.w)) : 0.f;
            Sp += (q0 + q1) + (q2 + q3);
            bm8[r][h * 1024 + t] = (unsigned char)nib;
            if (!h) {
                pq0 = q0; pq1 = q1; pq2 = q2; pq3 = q3;
            } else {
                // row r complete: flush partial, lgkm-barrier, normalize, write
                #pragma unroll
                for (int off = 32; off; off >>= 1) Sp += __shfl_xor(Sp, off);
                if (lane == 0) sm_Sp[r][w] = Sp;
                Sp = 0.f;
                asm volatile("s_waitcnt lgkmcnt(0)" ::: "memory");
                __builtin_amdgcn_s_barrier();
                float sv = 0.f;
                #pragma unroll
                for (int kk = 0; kk < 16; ++kk) sv += sm_Sp[r][kk];
                const float isr = 1.0f / sv;
                if (t == 0) sm_is[r] = isr;
                f4v sa; sa.x = pq0 * isr; sa.y = pq1 * isr;
                        sa.z = pq2 * isr; sa.w = pq3 * isr;
                f4v sb; sb.x = q0 * isr;  sb.y = q1 * isr;
                        sb.z = q2 * isr;  sb.w = q3 * isr;
                __builtin_nontemporal_store(sa, (f4v*)(attb + (size_t)r * Nn + j0));
                __builtin_nontemporal_store(sb, (f4v*)(attb + (size_t)r * Nn + 4096 + j0));
            }
        }
    }
    __syncthreads();

    const int row = row0 + w;
    const float h1 = Wh1[row];
    const float is = sm_is[w];

    // ---------------- Phase B: bf16 LDS tiles + MFMA PV (no stores) ---------
    const int ct = w & 3;    // col tile (16 cols)
    const int kq = w >> 2;   // k quarter (2 of 8 ksteps per chunk)
    f32x4 acc = {0.f, 0.f, 0.f, 0.f};

    auto produce = [&](int c, int bf) {
        const int jb = c * 256;
        const f4v w2 = *((const f4v*)(Wh2 + jb) + lane);
        const int nib = bm8[w][c * 64 + lane];
        const float v0 = (nib & 1) ? __expf(lrelu(h1 + w2.x)) * is : 0.f;
        const float v1 = (nib & 2) ? __expf(lrelu(h1 + w2.y)) * is : 0.f;
        const float v2 = (nib & 4) ? __expf(lrelu(h1 + w2.z)) * is : 0.f;
        const float v3 = (nib & 8) ? __expf(lrelu(h1 + w2.w)) * is : 0.f;
        const u64 pk = (u64)(f2bf(v0) | (f2bf(v1) << 16))
                     | ((u64)(f2bf(v2) | (f2bf(v3) << 16)) << 32);
        int byte = w * 512 + lane * 8;  byte ^= (w & 7) << 4;
        *(u64*)((char*)att_t[bf] + byte) = pk;
    };

    const int ar = lane & 15;    // MFMA A-row / B-row this lane reads
    const int ag = lane >> 4;    // k-subgroup
    auto bload = [&](int c, int ss) -> s8 {
        const int ks = kq * 2 + ss;
        return *(const s8*)(WhT + (size_t)(ct * 16 + ar) * Nn
                            + c * 256 + ks * 32 + ag * 8);
    };
    auto amfma = [&](int bf, s8 b0, s8 b1) {
        #pragma unroll
        for (int ss = 0; ss < 2; ++ss) {
            const int ks = kq * 2 + ss;
            int byte = ar * 512 + ks * 64 + ag * 16;
            byte ^= (ar & 7) << 4;
            const s8 af = *(const s8*)((char*)att_t[bf] + byte);
            acc = __builtin_amdgcn_mfma_f32_16x16x32_bf16(af, ss ? b1 : b0, acc, 0, 0, 0);
        }
    };

    s8 b0 = bload(0, 0), b1 = bload(0, 1);
    produce(0, 0);
    asm volatile("s_waitcnt lgkmcnt(0)" ::: "memory");
    __builtin_amdgcn_s_barrier();
    for (int c = 0; c < Nn / 256 - 1; ++c) {
        produce(c + 1, (c + 1) & 1);
        const s8 nb0 = bload(c + 1, 0);
        const s8 nb1 = bload(c + 1, 1);
        amfma(c & 1, b0, b1);
        asm volatile("s_waitcnt lgkmcnt(0)" ::: "memory");
        __builtin_amdgcn_s_barrier();
        b0 = nb0; b1 = nb1;
    }
    amfma((Nn / 256 - 1) & 1, b0, b1);

    // ---------------- Epilogue: kq reduce + ELU + out store -----------------
    __syncthreads();
    if (kq > 0) {
        #pragma unroll
        for (int q = 0; q < 4; ++q) red[kq - 1][ct][ag * 4 + q][ar] = acc[q];
    }
    __syncthreads();
    if (kq == 0) {
        #pragma unroll
        for (int q = 0; q < 4; ++q) {
            const int r = ag * 4 + q;
            float v = acc[q] + red[0][ct][r][ar] + red[1][ct][r][ar] + red[2][ct][r][ar];
            v = v > 0.f ? v : expm1f(v);
            outp[(size_t)(row0 + r) * OUTF + ct * 16 + ar] = v;
        }
    }
}

// ---------------------------------------------------------------------------
extern "C" void kernel_launch(void* const* d_in, const int* in_sizes, int n_in,
                              void* d_out, int out_size, void* d_ws, size_t ws_size,
                              hipStream_t stream)
{
    const float* x   = (const float*)d_in[0];
    const int*   adj = (const int*)d_in[1];
    const float* W   = (const float*)d_in[2];
    const float* a   = (const float*)d_in[3];

    float* outp = (float*)d_out;                       // [N, 64]
    float* att  = outp + (size_t)Nn * OUTF;            // [N, N]

    // workspace: Wh1, Wh2 (f32), WhT (bf16 [64][N])  ~1.06 MB
    float* Wh1 = (float*)d_ws;
    float* Wh2 = Wh1 + Nn;
    unsigned short* WhT = (unsigned short*)(Wh2 + Nn);

    hipLaunchKernelGGL(k1_wh,    dim3(Nn / 16), dim3(1024), 0, stream,
                       x, W, a, WhT, Wh1, Wh2);
    hipLaunchKernelGGL(k2_fused, dim3(Nn / 16), dim3(1024), 0, stream,
                       adj, WhT, Wh1, Wh2, outp, att);
}

// Round 21
// 176.121 us; speedup vs baseline: 1.0907x; 1.0907x over previous
//
#include <hip/hip_runtime.h>
#include <cmath>

#define Nn    8192
#define INF_  512
#define OUTF  64

typedef __attribute__((ext_vector_type(4))) int   i4;
typedef __attribute__((ext_vector_type(2))) float f2;
typedef __attribute__((ext_vector_type(4))) float f4v;
typedef __attribute__((ext_vector_type(8))) short s8;
typedef __attribute__((ext_vector_type(4))) float f32x4;
typedef unsigned long long u64;

__device__ __forceinline__ float lrelu(float v) { return fmaxf(v, 0.2f * v); }

__device__ __forceinline__ unsigned int f2bf(float f) {
    unsigned int u = __float_as_uint(f);
    u = (u + 0x7FFFu + ((u >> 16) & 1u)) >> 16;
    return u;
}

__device__ __forceinline__ u64 pack32(u64 v) {   // 8 nibble-bytes -> 32 bits
    v &= 0x0F0F0F0F0F0F0F0FULL;
    v = (v | (v >> 4))  & 0x00FF00FF00FF00FFULL;
    v = (v | (v >> 8))  & 0x0000FFFF0000FFFFULL;
    v = (v | (v >> 16)) & 0x00000000FFFFFFFFULL;
    return v;
}

// ---------------------------------------------------------------------------
// k1: Wh = x @ W -> WhT bf16 [64][N]; Wh1 = Wh@a[:64]; Wh2 = Wh@a[64:].
// DENSE x read (R15 exact). 1024 thr; grid N/16 = 512.  (~10-12 us)
// ---------------------------------------------------------------------------
__global__ __launch_bounds__(1024, 8) void k1_wh(
    const float* __restrict__ x, const float* __restrict__ W,
    const float* __restrict__ a, unsigned short* __restrict__ WhT,
    float* __restrict__ Wh1, float* __restrict__ Wh2)
{
    __shared__ float xs[16][520];             // 33.3 KB x slab (padded)
    __shared__ float part[3][16][64];         // 12 KB k-slice partials
    __shared__ unsigned short stage[64][16];  // 2 KB bf16 transpose stage
    const int t    = threadIdx.x;
    const int row0 = blockIdx.x * 16;

    #pragma unroll
    for (int s2 = 0; s2 < 2; ++s2) {
        const int idx = s2 * 4096 + 4 * t;
        const f4v v = __builtin_nontemporal_load(
            (const f4v*)(x + (size_t)row0 * INF_ + idx));
        *(f4v*)&xs[idx >> 9][idx & 511] = v;
    }
    __syncthreads();

    const int s    = t >> 8;                  // k-slice 0..3
    const int r    = (t >> 4) & 15;           // row
    const int cg   = (t & 15) << 2;           // col group (4 cols)
    const int row  = row0 + r;
    const float* __restrict__ Wp = W + (size_t)s * 128 * OUTF;

    float4 acc = make_float4(0.f, 0.f, 0.f, 0.f);
    for (int k = 0; k < 128; k += 4) {
        const float4 xv = *(const float4*)&xs[r][s * 128 + k];
        const float* wp = Wp + (size_t)k * OUTF + cg;
        const float4 w0 = *(const float4*)(wp);
        const float4 w1 = *(const float4*)(wp + OUTF);
        const float4 w2 = *(const float4*)(wp + 2 * OUTF);
        const float4 w3 = *(const float4*)(wp + 3 * OUTF);
        acc.x += xv.x * w0.x + xv.y * w1.x + xv.z * w2.x + xv.w * w3.x;
        acc.y += xv.x * w0.y + xv.y * w1.y + xv.z * w2.y + xv.w * w3.y;
        acc.z += xv.x * w0.z + xv.y * w1.z + xv.z * w2.z + xv.w * w3.z;
        acc.w += xv.x * w0.w + xv.y * w1.w + xv.z * w2.w + xv.w * w3.w;
    }
    if (s > 0) *(float4*)&part[s - 1][r][cg] = acc;
    __syncthreads();
    if (s == 0) {
        const float4 pa = *(const float4*)&part[0][r][cg];
        const float4 pb = *(const float4*)&part[1][r][cg];
        const float4 pc = *(const float4*)&part[2][r][cg];
        acc.x += pa.x + pb.x + pc.x;
        acc.y += pa.y + pb.y + pc.y;
        acc.z += pa.z + pb.z + pc.z;
        acc.w += pa.w + pb.w + pc.w;
        stage[cg + 0][r] = (unsigned short)f2bf(acc.x);
        stage[cg + 1][r] = (unsigned short)f2bf(acc.y);
        stage[cg + 2][r] = (unsigned short)f2bf(acc.z);
        stage[cg + 3][r] = (unsigned short)f2bf(acc.w);

        float p1 = acc.x * a[cg]        + acc.y * a[cg + 1]
                 + acc.z * a[cg + 2]    + acc.w * a[cg + 3];
        float p2 = acc.x * a[OUTF + cg]     + acc.y * a[OUTF + cg + 1]
                 + acc.z * a[OUTF + cg + 2] + acc.w * a[OUTF + cg + 3];
        #pragma unroll
        for (int off = 8; off; off >>= 1) {
            p1 += __shfl_xor(p1, off);
            p2 += __shfl_xor(p2, off);
        }
        if ((t & 15) == 0) { Wh1[row] = p1; Wh2[row] = p2; }
    }
    __syncthreads();
    if (t < 256) {
        const int col = t >> 2;
        const int q   = t & 3;
        const u64 v = *(const u64*)&stage[col][q * 4];
        *(u64*)(WhT + (size_t)col * Nn + row0 + q * 4) = v;
    }
}

// ---------------------------------------------------------------------------
// k2a: dense 3-deep adj scan (R19 phase A as standalone kernel).
// 16 rows/block, 1024 thr; emits bm_g [N][128] u64 + is_g[N] (no-max softmax
// denominators). Grid N/16 = 512.  (~60 us, read-BW bound)
// ---------------------------------------------------------------------------
__global__ __launch_bounds__(1024, 8) void k2a_scan(
    const int* __restrict__ adj, const float* __restrict__ Wh1,
    const float* __restrict__ Wh2, u64* __restrict__ bm_g,
    float* __restrict__ is_g)
{
    __shared__ unsigned char bm8[16][2048];   // 32 KB nibble masks
    __shared__ float sm_Sp[16][16];           // 1 KB

    const int t    = threadIdx.x;
    const int lane = t & 63;
    const int w    = t >> 6;
    const int row0 = blockIdx.x * 16;

    const int j0 = 4 * t;
    const f4v w4a = *(const f4v*)(Wh2 + j0);
    const f4v w4b = *(const f4v*)(Wh2 + 4096 + j0);

    {
        const i4* __restrict__ asrc = (const i4*)(adj + (size_t)row0 * Nn);
        float Sp = 0.f;
        i4 p0 = __builtin_nontemporal_load(asrc + t);
        i4 p1 = __builtin_nontemporal_load(asrc + 1024 + t);
        i4 p2 = __builtin_nontemporal_load(asrc + 2048 + t);
        #pragma unroll
        for (int s = 0; s < 32; ++s) {
            const int r = s >> 1, h = s & 1;
            const i4 av = p0;
            p0 = p1; p1 = p2;
            if (s < 29)
                p2 = __builtin_nontemporal_load(asrc + (s + 3) * 1024 + t);
            const f4v w4 = h ? w4b : w4a;
            const float h1r = Wh1[row0 + r];
            const int nib = (av.x != 0 ? 1 : 0) | (av.y != 0 ? 2 : 0)
                          | (av.z != 0 ? 4 : 0) | (av.w != 0 ? 8 : 0);
            Sp += (nib & 1) ? __expf(lrelu(h1r + w4.x)) : 0.f;
            Sp += (nib & 2) ? __expf(lrelu(h1r + w4.y)) : 0.f;
            Sp += (nib & 4) ? __expf(lrelu(h1r + w4.z)) : 0.f;
            Sp += (nib & 8) ? __expf(lrelu(h1r + w4.w)) : 0.f;
            bm8[r][h * 1024 + t] = (unsigned char)nib;
            if (h) {
                #pragma unroll
                for (int off = 32; off; off >>= 1) Sp += __shfl_xor(Sp, off);
                if (lane == 0) sm_Sp[r][w] = Sp;
                Sp = 0.f;
            }
        }
    }
    __syncthreads();

    // S finish: wave w reduces row w -> is_g
    {
        float sv = sm_Sp[w][lane & 15];
        #pragma unroll
        for (int off = 8; off; off >>= 1) sv += __shfl_xor(sv, off);
        if (lane == 0) is_g[row0 + w] = 1.0f / sv;
    }

    // pack nibble-bytes -> u64 bitmask words, coalesced store
    #pragma unroll
    for (int i = 0; i < 2; ++i) {
        const int wi = 2 * t + i;                 // 0..2047
        const int r  = wi >> 7, c = wi & 127;
        const u64 v0 = *(const u64*)&bm8[r][16 * c];
        const u64 v1 = *(const u64*)&bm8[r][16 * c + 8];
        bm_g[(size_t)(row0 + r) * 128 + c] = pack32(v0) | (pack32(v1) << 32);
    }
}

// ---------------------------------------------------------------------------
// k2b: att materialization + MFMA PV + ELU (R3's proven ~49us kernel,
// no-max variant). 512 thr = 8 waves; wave w -> rows {2w,2w+1}; 16 rows/blk;
// grid 512; chunk = 128 js; swizzled bf16 LDS dbuf; in-loop nt stores.
// ---------------------------------------------------------------------------
__global__ __launch_bounds__(512) void k2b_pv(
    const unsigned short* __restrict__ WhT, const float* __restrict__ Wh1,
    const float* __restrict__ Wh2, const u64* __restrict__ bm_g,
    const float* __restrict__ is_g,
    float* __restrict__ outp, float* __restrict__ att)
{
    __shared__ alignas(16) unsigned short att_t[2][16 * 128];  // 8 KB
    __shared__ float red[4][16][16];                           // 4 KB

    const int t    = threadIdx.x;
    const int lane = t & 63;
    const int w    = t >> 6;
    const int row0 = blockIdx.x * 16;

    const int rA = 2 * w, rB = 2 * w + 1;
    const float h1A = Wh1[row0 + rA], isA = is_g[row0 + rA];
    const float h1B = Wh1[row0 + rB], isB = is_g[row0 + rB];
    const u64* __restrict__ bmA = bm_g + (size_t)(row0 + rA) * (Nn / 64);
    const u64* __restrict__ bmB = bm_g + (size_t)(row0 + rB) * (Nn / 64);

    const int ct = w & 3;    // col tile (16 cols)
    const int kh = w >> 2;   // k half (2 of 4 ksteps per chunk)
    f32x4 acc = {0.f, 0.f, 0.f, 0.f};

    const int j2   = lane * 2;
    const int wsub = j2 >> 6;
    const int bit0 = j2 & 63;

    auto produce = [&](int c, int b) {
        const int jb = c * 128;
        const f2 w2 = *((const f2*)(Wh2 + jb) + lane);
        const int wi = (jb >> 6) + wsub;
        {
            const u64 bA = bmA[wi];
            const float v0 = ((bA >> bit0) & 1ull)       ? __expf(lrelu(h1A + w2.x)) * isA : 0.f;
            const float v1 = ((bA >> (bit0 + 1)) & 1ull) ? __expf(lrelu(h1A + w2.y)) * isA : 0.f;
            f2 st; st.x = v0; st.y = v1;
            __builtin_nontemporal_store(st, (f2*)(att + (size_t)(row0 + rA) * Nn + jb) + lane);
            const unsigned int pk = f2bf(v0) | (f2bf(v1) << 16);
            int byte = rA * 256 + j2 * 2;  byte ^= (rA & 7) << 4;
            *(unsigned int*)((char*)att_t[b] + byte) = pk;
        }
        {
            const u64 bB = bmB[wi];
            const float v0 = ((bB >> bit0) & 1ull)       ? __expf(lrelu(h1B + w2.x)) * isB : 0.f;
            const float v1 = ((bB >> (bit0 + 1)) & 1ull) ? __expf(lrelu(h1B + w2.y)) * isB : 0.f;
            f2 st; st.x = v0; st.y = v1;
            __builtin_nontemporal_store(st, (f2*)(att + (size_t)(row0 + rB) * Nn + jb) + lane);
            const unsigned int pk = f2bf(v0) | (f2bf(v1) << 16);
            int byte = rB * 256 + j2 * 2;  byte ^= (rB & 7) << 4;
            *(unsigned int*)((char*)att_t[b] + byte) = pk;
        }
    };

    const int arow = lane & 15;
    const int agrp = lane >> 4;
    auto domfma = [&](int c, int b) {
        const int jb = c * 128;
        #pragma unroll
        for (int s = 0; s < 2; ++s) {
            const int ks = kh * 2 + s;
            int byte = arow * 256 + ks * 64 + agrp * 16;
            byte ^= (arow & 7) << 4;
            const s8 afrag = *(const s8*)((char*)att_t[b] + byte);
            const s8 bfrag = *(const s8*)(WhT + (size_t)(ct * 16 + arow) * Nn
                                          + jb + ks * 32 + agrp * 8);
            acc = __builtin_amdgcn_mfma_f32_16x16x32_bf16(afrag, bfrag, acc, 0, 0, 0);
        }
    };

    produce(0, 0);
    __syncthreads();
    for (int c = 0; c < Nn / 128 - 1; ++c) {
        produce(c + 1, (c + 1) & 1);
        domfma(c, c & 1);
        __syncthreads();
    }
    domfma(Nn / 128 - 1, (Nn / 128 - 1) & 1);

    __syncthreads();
    if (kh == 1) {
        #pragma unroll
        for (int q = 0; q < 4; ++q) red[ct][agrp * 4 + q][arow] = acc[q];
    }
    __syncthreads();
    if (kh == 0) {
        #pragma unroll
        for (int q = 0; q < 4; ++q) {
            float v = acc[q] + red[ct][agrp * 4 + q][arow];
            v = v > 0.f ? v : expm1f(v);
            outp[(size_t)(row0 + agrp * 4 + q) * OUTF + ct * 16 + arow] = v;
        }
    }
}

// ---------------------------------------------------------------------------
extern "C" void kernel_launch(void* const* d_in, const int* in_sizes, int n_in,
                              void* d_out, int out_size, void* d_ws, size_t ws_size,
                              hipStream_t stream)
{
    const float* x   = (const float*)d_in[0];
    const int*   adj = (const int*)d_in[1];
    const float* W   = (const float*)d_in[2];
    const float* a   = (const float*)d_in[3];

    float* outp = (float*)d_out;                       // [N, 64]
    float* att  = outp + (size_t)Nn * OUTF;            // [N, N]

    // workspace: Wh1, Wh2, is_g (f32), WhT (bf16 [64][N]), bm_g (8 MB)
    float* Wh1  = (float*)d_ws;
    float* Wh2  = Wh1 + Nn;
    float* is_g = Wh2 + Nn;
    unsigned short* WhT = (unsigned short*)(is_g + Nn);
    u64* bm_g = (u64*)(WhT + (size_t)OUTF * Nn);

    hipLaunchKernelGGL(k1_wh,    dim3(Nn / 16), dim3(1024), 0, stream,
                       x, W, a, WhT, Wh1, Wh2);
    hipLaunchKernelGGL(k2a_scan, dim3(Nn / 16), dim3(1024), 0, stream,
                       adj, Wh1, Wh2, bm_g, is_g);
    hipLaunchKernelGGL(k2b_pv,   dim3(Nn / 16), dim3(512), 0, stream,
                       WhT, Wh1, Wh2, bm_g, is_g, outp, att);
}

// Round 22
// 156.547 us; speedup vs baseline: 1.2271x; 1.1250x over previous
//
#include <hip/hip_runtime.h>
#include <cmath>

#define Nn    8192
#define INF_  512
#define OUTF  64

typedef __attribute__((ext_vector_type(4))) int   i4;
typedef __attribute__((ext_vector_type(4))) float f4v;
typedef __attribute__((ext_vector_type(8))) short s8;
typedef __attribute__((ext_vector_type(4))) float f32x4;
typedef unsigned long long u64;

__device__ __forceinline__ float lrelu(float v) { return fmaxf(v, 0.2f * v); }

__device__ __forceinline__ unsigned int f2bf(float f) {
    unsigned int u = __float_as_uint(f);
    u = (u + 0x7FFFu + ((u >> 16) & 1u)) >> 16;
    return u;
}

// XCD-aware bijective swizzle: grid 512, 8 XCDs, 64 blocks/XCD contiguous.
__device__ __forceinline__ int xcd_swizzle(int bid) {
    return (bid & 7) * 64 + (bid >> 3);
}

// ---------------------------------------------------------------------------
// k1: Wh = x @ W -> WhT bf16 [64][N]; Wh1 = Wh@a[:64]; Wh2 = Wh@a[64:].
// DENSE x read (R15 exact) + XCD swizzle. 1024 thr; grid N/16 = 512.
// ---------------------------------------------------------------------------
__global__ __launch_bounds__(1024, 8) void k1_wh(
    const float* __restrict__ x, const float* __restrict__ W,
    const float* __restrict__ a, unsigned short* __restrict__ WhT,
    float* __restrict__ Wh1, float* __restrict__ Wh2)
{
    __shared__ float xs[16][520];             // 33.3 KB x slab (padded)
    __shared__ float part[3][16][64];         // 12 KB k-slice partials
    __shared__ unsigned short stage[64][16];  // 2 KB bf16 transpose stage
    const int t    = threadIdx.x;
    const int row0 = xcd_swizzle(blockIdx.x) * 16;

    #pragma unroll
    for (int s2 = 0; s2 < 2; ++s2) {
        const int idx = s2 * 4096 + 4 * t;
        const f4v v = __builtin_nontemporal_load(
            (const f4v*)(x + (size_t)row0 * INF_ + idx));
        *(f4v*)&xs[idx >> 9][idx & 511] = v;
    }
    __syncthreads();

    const int s    = t >> 8;                  // k-slice 0..3
    const int r    = (t >> 4) & 15;           // row
    const int cg   = (t & 15) << 2;           // col group (4 cols)
    const int row  = row0 + r;
    const float* __restrict__ Wp = W + (size_t)s * 128 * OUTF;

    float4 acc = make_float4(0.f, 0.f, 0.f, 0.f);
    for (int k = 0; k < 128; k += 4) {
        const float4 xv = *(const float4*)&xs[r][s * 128 + k];
        const float* wp = Wp + (size_t)k * OUTF + cg;
        const float4 w0 = *(const float4*)(wp);
        const float4 w1 = *(const float4*)(wp + OUTF);
        const float4 w2 = *(const float4*)(wp + 2 * OUTF);
        const float4 w3 = *(const float4*)(wp + 3 * OUTF);
        acc.x += xv.x * w0.x + xv.y * w1.x + xv.z * w2.x + xv.w * w3.x;
        acc.y += xv.x * w0.y + xv.y * w1.y + xv.z * w2.y + xv.w * w3.y;
        acc.z += xv.x * w0.z + xv.y * w1.z + xv.z * w2.z + xv.w * w3.z;
        acc.w += xv.x * w0.w + xv.y * w1.w + xv.z * w2.w + xv.w * w3.w;
    }
    if (s > 0) *(float4*)&part[s - 1][r][cg] = acc;
    __syncthreads();
    if (s == 0) {
        const float4 pa = *(const float4*)&part[0][r][cg];
        const float4 pb = *(const float4*)&part[1][r][cg];
        const float4 pc = *(const float4*)&part[2][r][cg];
        acc.x += pa.x + pb.x + pc.x;
        acc.y += pa.y + pb.y + pc.y;
        acc.z += pa.z + pb.z + pc.z;
        acc.w += pa.w + pb.w + pc.w;
        stage[cg + 0][r] = (unsigned short)f2bf(acc.x);
        stage[cg + 1][r] = (unsigned short)f2bf(acc.y);
        stage[cg + 2][r] = (unsigned short)f2bf(acc.z);
        stage[cg + 3][r] = (unsigned short)f2bf(acc.w);

        float p1 = acc.x * a[cg]        + acc.y * a[cg + 1]
                 + acc.z * a[cg + 2]    + acc.w * a[cg + 3];
        float p2 = acc.x * a[OUTF + cg]     + acc.y * a[OUTF + cg + 1]
                 + acc.z * a[OUTF + cg + 2] + acc.w * a[OUTF + cg + 3];
        #pragma unroll
        for (int off = 8; off; off >>= 1) {
            p1 += __shfl_xor(p1, off);
            p2 += __shfl_xor(p2, off);
        }
        if ((t & 15) == 0) { Wh1[row] = p1; Wh2[row] = p2; }
    }
    __syncthreads();
    if (t < 256) {
        const int col = t >> 2;
        const int q   = t & 3;
        const u64 v = *(const u64*)&stage[col][q * 4];
        *(u64*)(WhT + (size_t)col * Nn + row0 + q * 4) = v;
    }
}

// ---------------------------------------------------------------------------
// k2: FUSED (R19 exact + XCD swizzle), 16 rows/block, 1024 thr = 16 waves.
//  Phase A: dense 3-deep pipelined adj sweep -> bm8 + per-row exp-sums.
//  S-finish: wave w reduces row w -> sm_is[w].
//  Phase B: per 256-j chunk: att = bit?exp*is:0; f32 nt store in-loop +
//    bf16 XOR-swizzled LDS tile dbuf; 2 mfma/chunk; 1-chunk b-frag prefetch;
//    lgkmcnt(0)+s_barrier per chunk.
//  Epilogue: 4-way kq reduce, ELU, store out.
// ---------------------------------------------------------------------------
__global__ __launch_bounds__(1024, 8) void k2_fused(
    const int* __restrict__ adj, const unsigned short* __restrict__ WhT,
    const float* __restrict__ Wh1, const float* __restrict__ Wh2,
    float* __restrict__ outp, float* __restrict__ att)
{
    __shared__ unsigned char bm8[16][2048];                    // 32 KB masks
    __shared__ alignas(16) unsigned short att_t[2][16 * 256];  // 16 KB
    __shared__ float red[3][4][16][16];                        // 12 KB
    __shared__ float sm_Sp[16][16];                            // 1 KB
    __shared__ float sm_is[16];

    const int t    = threadIdx.x;
    const int lane = t & 63;
    const int w    = t >> 6;               // wave id; phase B row = w
    const int row0 = xcd_swizzle(blockIdx.x) * 16;

    const int j0 = 4 * t;                  // this thread's j within half-row
    const f4v w4a = *(const f4v*)(Wh2 + j0);          // half 0 cols
    const f4v w4b = *(const f4v*)(Wh2 + 4096 + j0);   // half 1 cols

    // ---------------- Phase A: dense sweep, 3-deep pipeline -----------------
    {
        const i4* __restrict__ asrc = (const i4*)(adj + (size_t)row0 * Nn);
        float Sp = 0.f;
        i4 p0 = __builtin_nontemporal_load(asrc + t);
        i4 p1 = __builtin_nontemporal_load(asrc + 1024 + t);
        i4 p2 = __builtin_nontemporal_load(asrc + 2048 + t);
        #pragma unroll
        for (int s = 0; s < 32; ++s) {
            const int r = s >> 1, h = s & 1;
            const i4 av = p0;
            p0 = p1; p1 = p2;
            if (s < 29)
                p2 = __builtin_nontemporal_load(asrc + (s + 3) * 1024 + t);
            const f4v w4 = h ? w4b : w4a;
            const float h1r = Wh1[row0 + r];
            const int nib = (av.x != 0 ? 1 : 0) | (av.y != 0 ? 2 : 0)
                          | (av.z != 0 ? 4 : 0) | (av.w != 0 ? 8 : 0);
            Sp += (nib & 1) ? __expf(lrelu(h1r + w4.x)) : 0.f;
            Sp += (nib & 2) ? __expf(lrelu(h1r + w4.y)) : 0.f;
            Sp += (nib & 4) ? __expf(lrelu(h1r + w4.z)) : 0.f;
            Sp += (nib & 8) ? __expf(lrelu(h1r + w4.w)) : 0.f;
            bm8[r][h * 1024 + t] = (unsigned char)nib;
            if (h) {   // row r complete for this thread: flush partial
                #pragma unroll
                for (int off = 32; off; off >>= 1) Sp += __shfl_xor(Sp, off);
                if (lane == 0) sm_Sp[r][w] = Sp;
                Sp = 0.f;
            }
        }
    }
    __syncthreads();

    // ---------------- S finish: wave w reduces row w ------------------------
    {
        float sv = sm_Sp[w][lane & 15];
        #pragma unroll
        for (int off = 8; off; off >>= 1) sv += __shfl_xor(sv, off);
        if (lane == 0) sm_is[w] = 1.0f / sv;
    }
    __syncthreads();

    const int row = row0 + w;
    const float h1 = Wh1[row];
    const float is = sm_is[w];

    // ---------------- Phase B: att stores + bf16 LDS + MFMA PV --------------
    const int ct = w & 3;    // col tile (16 cols)
    const int kq = w >> 2;   // k quarter (2 of 8 ksteps per chunk)
    f32x4 acc = {0.f, 0.f, 0.f, 0.f};

    auto produce = [&](int c, int bf) {
        const int jb = c * 256;
        const f4v w2 = *((const f4v*)(Wh2 + jb) + lane);
        const int nib = bm8[w][c * 64 + lane];
        const float v0 = (nib & 1) ? __expf(lrelu(h1 + w2.x)) * is : 0.f;
        const float v1 = (nib & 2) ? __expf(lrelu(h1 + w2.y)) * is : 0.f;
        const float v2 = (nib & 4) ? __expf(lrelu(h1 + w2.z)) * is : 0.f;
        const float v3 = (nib & 8) ? __expf(lrelu(h1 + w2.w)) * is : 0.f;
        f4v st; st.x = v0; st.y = v1; st.z = v2; st.w = v3;
        __builtin_nontemporal_store(st, (f4v*)(att + (size_t)row * Nn + jb) + lane);
        const u64 pk = (u64)(f2bf(v0) | (f2bf(v1) << 16))
                     | ((u64)(f2bf(v2) | (f2bf(v3) << 16)) << 32);
        int byte = w * 512 + lane * 8;  byte ^= (w & 7) << 4;
        *(u64*)((char*)att_t[bf] + byte) = pk;
    };

    const int ar = lane & 15;    // MFMA A-row / B-row this lane reads
    const int ag = lane >> 4;    // k-subgroup
    auto bload = [&](int c, int ss) -> s8 {
        const int ks = kq * 2 + ss;
        return *(const s8*)(WhT + (size_t)(ct * 16 + ar) * Nn
                            + c * 256 + ks * 32 + ag * 8);
    };
    auto amfma = [&](int bf, s8 b0, s8 b1) {
        #pragma unroll
        for (int ss = 0; ss < 2; ++ss) {
            const int ks = kq * 2 + ss;
            int byte = ar * 512 + ks * 64 + ag * 16;
            byte ^= (ar & 7) << 4;
            const s8 af = *(const s8*)((char*)att_t[bf] + byte);
            acc = __builtin_amdgcn_mfma_f32_16x16x32_bf16(af, ss ? b1 : b0, acc, 0, 0, 0);
        }
    };

    s8 b0 = bload(0, 0), b1 = bload(0, 1);
    produce(0, 0);
    asm volatile("s_waitcnt lgkmcnt(0)" ::: "memory");
    __builtin_amdgcn_s_barrier();
    for (int c = 0; c < Nn / 256 - 1; ++c) {
        produce(c + 1, (c + 1) & 1);
        const s8 nb0 = bload(c + 1, 0);
        const s8 nb1 = bload(c + 1, 1);
        amfma(c & 1, b0, b1);
        asm volatile("s_waitcnt lgkmcnt(0)" ::: "memory");
        __builtin_amdgcn_s_barrier();
        b0 = nb0; b1 = nb1;
    }
    amfma((Nn / 256 - 1) & 1, b0, b1);

    // ---------------- Epilogue: kq reduce + ELU + out store -----------------
    __syncthreads();
    if (kq > 0) {
        #pragma unroll
        for (int q = 0; q < 4; ++q) red[kq - 1][ct][ag * 4 + q][ar] = acc[q];
    }
    __syncthreads();
    if (kq == 0) {
        #pragma unroll
        for (int q = 0; q < 4; ++q) {
            const int r = ag * 4 + q;
            float v = acc[q] + red[0][ct][r][ar] + red[1][ct][r][ar] + red[2][ct][r][ar];
            v = v > 0.f ? v : expm1f(v);
            outp[(size_t)(row0 + r) * OUTF + ct * 16 + ar] = v;
        }
    }
}

// ---------------------------------------------------------------------------
extern "C" void kernel_launch(void* const* d_in, const int* in_sizes, int n_in,
                              void* d_out, int out_size, void* d_ws, size_t ws_size,
                              hipStream_t stream)
{
    const float* x   = (const float*)d_in[0];
    const int*   adj = (const int*)d_in[1];
    const float* W   = (const float*)d_in[2];
    const float* a   = (const float*)d_in[3];

    float* outp = (float*)d_out;                       // [N, 64]
    float* att  = outp + (size_t)Nn * OUTF;            // [N, N]

    // workspace: Wh1, Wh2 (f32), WhT (bf16 [64][N])  ~1.06 MB
    float* Wh1 = (float*)d_ws;
    float* Wh2 = Wh1 + Nn;
    unsigned short* WhT = (unsigned short*)(Wh2 + Nn);

    hipLaunchKernelGGL(k1_wh,    dim3(Nn / 16), dim3(1024), 0, stream,
                       x, W, a, WhT, Wh1, Wh2);
    hipLaunchKernelGGL(k2_fused, dim3(Nn / 16), dim3(1024), 0, stream,
                       adj, WhT, Wh1, Wh2, outp, att);
}

// Round 23
// 156.306 us; speedup vs baseline: 1.2290x; 1.0015x over previous
//
#include <hip/hip_runtime.h>
#include <cmath>

#define Nn    8192
#define INF_  512
#define OUTF  64

typedef __attribute__((ext_vector_type(4))) int   i4;
typedef __attribute__((ext_vector_type(4))) float f4v;
typedef __attribute__((ext_vector_type(8))) short s8;
typedef __attribute__((ext_vector_type(4))) float f32x4;
typedef unsigned long long u64;

__device__ __forceinline__ float lrelu(float v) { return fmaxf(v, 0.2f * v); }

__device__ __forceinline__ unsigned int f2bf(float f) {
    unsigned int u = __float_as_uint(f);
    u = (u + 0x7FFFu + ((u >> 16) & 1u)) >> 16;
    return u;
}

// XCD-aware bijective swizzle: grid 512, 8 XCDs, 64 blocks/XCD contiguous.
__device__ __forceinline__ int xcd_swizzle(int bid) {
    return (bid & 7) * 64 + (bid >> 3);
}

// ---------------------------------------------------------------------------
// k1: Wh = x @ W -> WhT bf16 [64][N]; Wh1 = Wh@a[:64]; Wh2 = Wh@a[64:].
// DENSE x read (R15 exact) + XCD swizzle. 1024 thr; grid N/16 = 512.
// ---------------------------------------------------------------------------
__global__ __launch_bounds__(1024, 8) void k1_wh(
    const float* __restrict__ x, const float* __restrict__ W,
    const float* __restrict__ a, unsigned short* __restrict__ WhT,
    float* __restrict__ Wh1, float* __restrict__ Wh2)
{
    __shared__ float xs[16][520];             // 33.3 KB x slab (padded)
    __shared__ float part[3][16][64];         // 12 KB k-slice partials
    __shared__ unsigned short stage[64][16];  // 2 KB bf16 transpose stage
    const int t    = threadIdx.x;
    const int row0 = xcd_swizzle(blockIdx.x) * 16;

    #pragma unroll
    for (int s2 = 0; s2 < 2; ++s2) {
        const int idx = s2 * 4096 + 4 * t;
        const f4v v = __builtin_nontemporal_load(
            (const f4v*)(x + (size_t)row0 * INF_ + idx));
        *(f4v*)&xs[idx >> 9][idx & 511] = v;
    }
    __syncthreads();

    const int s    = t >> 8;                  // k-slice 0..3
    const int r    = (t >> 4) & 15;           // row
    const int cg   = (t & 15) << 2;           // col group (4 cols)
    const int row  = row0 + r;
    const float* __restrict__ Wp = W + (size_t)s * 128 * OUTF;

    float4 acc = make_float4(0.f, 0.f, 0.f, 0.f);
    for (int k = 0; k < 128; k += 4) {
        const float4 xv = *(const float4*)&xs[r][s * 128 + k];
        const float* wp = Wp + (size_t)k * OUTF + cg;
        const float4 w0 = *(const float4*)(wp);
        const float4 w1 = *(const float4*)(wp + OUTF);
        const float4 w2 = *(const float4*)(wp + 2 * OUTF);
        const float4 w3 = *(const float4*)(wp + 3 * OUTF);
        acc.x += xv.x * w0.x + xv.y * w1.x + xv.z * w2.x + xv.w * w3.x;
        acc.y += xv.x * w0.y + xv.y * w1.y + xv.z * w2.y + xv.w * w3.y;
        acc.z += xv.x * w0.z + xv.y * w1.z + xv.z * w2.z + xv.w * w3.z;
        acc.w += xv.x * w0.w + xv.y * w1.w + xv.z * w2.w + xv.w * w3.w;
    }
    if (s > 0) *(float4*)&part[s - 1][r][cg] = acc;
    __syncthreads();
    if (s == 0) {
        const float4 pa = *(const float4*)&part[0][r][cg];
        const float4 pb = *(const float4*)&part[1][r][cg];
        const float4 pc = *(const float4*)&part[2][r][cg];
        acc.x += pa.x + pb.x + pc.x;
        acc.y += pa.y + pb.y + pc.y;
        acc.z += pa.z + pb.z + pc.z;
        acc.w += pa.w + pb.w + pc.w;
        stage[cg + 0][r] = (unsigned short)f2bf(acc.x);
        stage[cg + 1][r] = (unsigned short)f2bf(acc.y);
        stage[cg + 2][r] = (unsigned short)f2bf(acc.z);
        stage[cg + 3][r] = (unsigned short)f2bf(acc.w);

        float p1 = acc.x * a[cg]        + acc.y * a[cg + 1]
                 + acc.z * a[cg + 2]    + acc.w * a[cg + 3];
        float p2 = acc.x * a[OUTF + cg]     + acc.y * a[OUTF + cg + 1]
                 + acc.z * a[OUTF + cg + 2] + acc.w * a[OUTF + cg + 3];
        #pragma unroll
        for (int off = 8; off; off >>= 1) {
            p1 += __shfl_xor(p1, off);
            p2 += __shfl_xor(p2, off);
        }
        if ((t & 15) == 0) { Wh1[row] = p1; Wh2[row] = p2; }
    }
    __syncthreads();
    if (t < 256) {
        const int col = t >> 2;
        const int q   = t & 3;
        const u64 v = *(const u64*)&stage[col][q * 4];
        *(u64*)(WhT + (size_t)col * Nn + row0 + q * 4) = v;
    }
}

// ---------------------------------------------------------------------------
// k2: FUSED (R22 exact, except att stores are PLAIN — the single lever).
// 16 rows/block, 1024 thr = 16 waves, XCD-swizzled grid 512.
//  Phase A: dense 3-deep pipelined adj sweep -> bm8 + per-row exp-sums.
//  S-finish: wave w reduces row w -> sm_is[w].
//  Phase B: per 256-j chunk: att = bit?exp*is:0; f32 PLAIN store in-loop
//    (L2 write aggregation; nt bypassed L2 and was never isolated) + bf16
//    XOR-swizzled LDS tile dbuf; 2 mfma/chunk; 1-chunk b-frag prefetch;
//    lgkmcnt(0)+s_barrier per chunk.
//  Epilogue: 4-way kq reduce, ELU, store out.
// ---------------------------------------------------------------------------
__global__ __launch_bounds__(1024, 8) void k2_fused(
    const int* __restrict__ adj, const unsigned short* __restrict__ WhT,
    const float* __restrict__ Wh1, const float* __restrict__ Wh2,
    float* __restrict__ outp, float* __restrict__ att)
{
    __shared__ unsigned char bm8[16][2048];                    // 32 KB masks
    __shared__ alignas(16) unsigned short att_t[2][16 * 256];  // 16 KB
    __shared__ float red[3][4][16][16];                        // 12 KB
    __shared__ float sm_Sp[16][16];                            // 1 KB
    __shared__ float sm_is[16];

    const int t    = threadIdx.x;
    const int lane = t & 63;
    const int w    = t >> 6;               // wave id; phase B row = w
    const int row0 = xcd_swizzle(blockIdx.x) * 16;

    const int j0 = 4 * t;                  // this thread's j within half-row
    const f4v w4a = *(const f4v*)(Wh2 + j0);          // half 0 cols
    const f4v w4b = *(const f4v*)(Wh2 + 4096 + j0);   // half 1 cols

    // ---------------- Phase A: dense sweep, 3-deep pipeline -----------------
    {
        const i4* __restrict__ asrc = (const i4*)(adj + (size_t)row0 * Nn);
        float Sp = 0.f;
        i4 p0 = __builtin_nontemporal_load(asrc + t);
        i4 p1 = __builtin_nontemporal_load(asrc + 1024 + t);
        i4 p2 = __builtin_nontemporal_load(asrc + 2048 + t);
        #pragma unroll
        for (int s = 0; s < 32; ++s) {
            const int r = s >> 1, h = s & 1;
            const i4 av = p0;
            p0 = p1; p1 = p2;
            if (s < 29)
                p2 = __builtin_nontemporal_load(asrc + (s + 3) * 1024 + t);
            const f4v w4 = h ? w4b : w4a;
            const float h1r = Wh1[row0 + r];
            const int nib = (av.x != 0 ? 1 : 0) | (av.y != 0 ? 2 : 0)
                          | (av.z != 0 ? 4 : 0) | (av.w != 0 ? 8 : 0);
            Sp += (nib & 1) ? __expf(lrelu(h1r + w4.x)) : 0.f;
            Sp += (nib & 2) ? __expf(lrelu(h1r + w4.y)) : 0.f;
            Sp += (nib & 4) ? __expf(lrelu(h1r + w4.z)) : 0.f;
            Sp += (nib & 8) ? __expf(lrelu(h1r + w4.w)) : 0.f;
            bm8[r][h * 1024 + t] = (unsigned char)nib;
            if (h) {   // row r complete for this thread: flush partial
                #pragma unroll
                for (int off = 32; off; off >>= 1) Sp += __shfl_xor(Sp, off);
                if (lane == 0) sm_Sp[r][w] = Sp;
                Sp = 0.f;
            }
        }
    }
    __syncthreads();

    // ---------------- S finish: wave w reduces row w ------------------------
    {
        float sv = sm_Sp[w][lane & 15];
        #pragma unroll
        for (int off = 8; off; off >>= 1) sv += __shfl_xor(sv, off);
        if (lane == 0) sm_is[w] = 1.0f / sv;
    }
    __syncthreads();

    const int row = row0 + w;
    const float h1 = Wh1[row];
    const float is = sm_is[w];

    // ---------------- Phase B: att stores + bf16 LDS + MFMA PV --------------
    const int ct = w & 3;    // col tile (16 cols)
    const int kq = w >> 2;   // k quarter (2 of 8 ksteps per chunk)
    f32x4 acc = {0.f, 0.f, 0.f, 0.f};

    auto produce = [&](int c, int bf) {
        const int jb = c * 256;
        const f4v w2 = *((const f4v*)(Wh2 + jb) + lane);
        const int nib = bm8[w][c * 64 + lane];
        const float v0 = (nib & 1) ? __expf(lrelu(h1 + w2.x)) * is : 0.f;
        const float v1 = (nib & 2) ? __expf(lrelu(h1 + w2.y)) * is : 0.f;
        const float v2 = (nib & 4) ? __expf(lrelu(h1 + w2.z)) * is : 0.f;
        const float v3 = (nib & 8) ? __expf(lrelu(h1 + w2.w)) * is : 0.f;
        f4v st; st.x = v0; st.y = v1; st.z = v2; st.w = v3;
        *((f4v*)(att + (size_t)row * Nn + jb) + lane) = st;   // PLAIN store
        const u64 pk = (u64)(f2bf(v0) | (f2bf(v1) << 16))
                     | ((u64)(f2bf(v2) | (f2bf(v3) << 16)) << 32);
        int byte = w * 512 + lane * 8;  byte ^= (w & 7) << 4;
        *(u64*)((char*)att_t[bf] + byte) = pk;
    };

    const int ar = lane & 15;    // MFMA A-row / B-row this lane reads
    const int ag = lane >> 4;    // k-subgroup
    auto bload = [&](int c, int ss) -> s8 {
        const int ks = kq * 2 + ss;
        return *(const s8*)(WhT + (size_t)(ct * 16 + ar) * Nn
                            + c * 256 + ks * 32 + ag * 8);
    };
    auto amfma = [&](int bf, s8 b0, s8 b1) {
        #pragma unroll
        for (int ss = 0; ss < 2; ++ss) {
            const int ks = kq * 2 + ss;
            int byte = ar * 512 + ks * 64 + ag * 16;
            byte ^= (ar & 7) << 4;
            const s8 af = *(const s8*)((char*)att_t[bf] + byte);
            acc = __builtin_amdgcn_mfma_f32_16x16x32_bf16(af, ss ? b1 : b0, acc, 0, 0, 0);
        }
    };

    s8 b0 = bload(0, 0), b1 = bload(0, 1);
    produce(0, 0);
    asm volatile("s_waitcnt lgkmcnt(0)" ::: "memory");
    __builtin_amdgcn_s_barrier();
    for (int c = 0; c < Nn / 256 - 1; ++c) {
        produce(c + 1, (c + 1) & 1);
        const s8 nb0 = bload(c + 1, 0);
        const s8 nb1 = bload(c + 1, 1);
        amfma(c & 1, b0, b1);
        asm volatile("s_waitcnt lgkmcnt(0)" ::: "memory");
        __builtin_amdgcn_s_barrier();
        b0 = nb0; b1 = nb1;
    }
    amfma((Nn / 256 - 1) & 1, b0, b1);

    // ---------------- Epilogue: kq reduce + ELU + out store -----------------
    __syncthreads();
    if (kq > 0) {
        #pragma unroll
        for (int q = 0; q < 4; ++q) red[kq - 1][ct][ag * 4 + q][ar] = acc[q];
    }
    __syncthreads();
    if (kq == 0) {
        #pragma unroll
        for (int q = 0; q < 4; ++q) {
            const int r = ag * 4 + q;
            float v = acc[q] + red[0][ct][r][ar] + red[1][ct][r][ar] + red[2][ct][r][ar];
            v = v > 0.f ? v : expm1f(v);
            outp[(size_t)(row0 + r) * OUTF + ct * 16 + ar] = v;
        }
    }
}

// ---------------------------------------------------------------------------
extern "C" void kernel_launch(void* const* d_in, const int* in_sizes, int n_in,
                              void* d_out, int out_size, void* d_ws, size_t ws_size,
                              hipStream_t stream)
{
    const float* x   = (const float*)d_in[0];
    const int*   adj = (const int*)d_in[1];
    const float* W   = (const float*)d_in[2];
    const float* a   = (const float*)d_in[3];

    float* outp = (float*)d_out;                       // [N, 64]
    float* att  = outp + (size_t)Nn * OUTF;            // [N, N]

    // workspace: Wh1, Wh2 (f32), WhT (bf16 [64][N])  ~1.06 MB
    float* Wh1 = (float*)d_ws;
    float* Wh2 = Wh1 + Nn;
    unsigned short* WhT = (unsigned short*)(Wh2 + Nn);

    hipLaunchKernelGGL(k1_wh,    dim3(Nn / 16), dim3(1024), 0, stream,
                       x, W, a, WhT, Wh1, Wh2);
    hipLaunchKernelGGL(k2_fused, dim3(Nn / 16), dim3(1024), 0, stream,
                       adj, WhT, Wh1, Wh2, outp, att);
}